// Round 1
// baseline (161.956 us; speedup 1.0000x reference)
//
#include <hip/hip_runtime.h>
#include <hip/hip_bf16.h>
#include <cstdint>
#include <cstddef>

#define T_DIM 2048
#define C_DIM 1024
#define NH 16
#define HS 64
#define KSP 64

// QKV GEMM: 128x64 tile, BK=128, XOR-swizzled LDS, global_load_lds staging
#define GBM 128
#define GBN 64
#define GBK 128
// o-proj GEMM: 64x64 tile (512 blocks = 2/CU)
#define OBM 64
#define OBN 64

typedef short short8 __attribute__((ext_vector_type(8)));
typedef float f32x4 __attribute__((ext_vector_type(4)));
typedef _Float16 half2_t __attribute__((ext_vector_type(2)));

__device__ __forceinline__ float bfu2f(unsigned short u) {
  unsigned v = ((unsigned)u) << 16;
  return __builtin_bit_cast(float, v);
}
__device__ __forceinline__ unsigned short f2bfu(float f) {
  unsigned u = __builtin_bit_cast(unsigned, f);
  unsigned r = (u + 0x7fffu + ((u >> 16) & 1u)) >> 16;
  return (unsigned short)r;
}
__device__ __forceinline__ unsigned short f2h(float f) {
  _Float16 h = (_Float16)f;
  return __builtin_bit_cast(unsigned short, h);
}
__device__ __forceinline__ float bflo(unsigned u) {
  return __builtin_bit_cast(float, u << 16);
}
__device__ __forceinline__ float bfhi(unsigned u) {
  return __builtin_bit_cast(float, u & 0xffff0000u);
}

__device__ __forceinline__ float dot2h(unsigned kbits, unsigned qbits, float acc) {
#if __has_builtin(__builtin_amdgcn_fdot2)
  return __builtin_amdgcn_fdot2(__builtin_bit_cast(half2_t, kbits),
                                __builtin_bit_cast(half2_t, qbits), acc, false);
#else
  half2_t kk = __builtin_bit_cast(half2_t, kbits);
  half2_t qq = __builtin_bit_cast(half2_t, qbits);
  return acc + (float)kk.x * (float)qq.x + (float)kk.y * (float)qq.y;
#endif
}

#define GLOAD_LDS16(gp, lp)                                                  \
  __builtin_amdgcn_global_load_lds(                                          \
      (const __attribute__((address_space(1))) void*)(gp),                   \
      (__attribute__((address_space(3))) void*)(lp), 16, 0, 0)

// ---- launch 1: key_scores (blocks [0,512)) + f32->bf16 conversion (rest) ----
#define NSCORE (T_DIM / 4)  // 512
#define NCONV ((T_DIM * C_DIM + 4 * C_DIM * C_DIM) / 4 / 256)  // 6144
__global__ __launch_bounds__(256) void convert_scores_kernel(
    const float* __restrict__ x, const float* __restrict__ Wq,
    const float* __restrict__ Wk, const float* __restrict__ Wv,
    const float* __restrict__ Wo, const float* __restrict__ Wks,
    const float* __restrict__ bks,
    unsigned short* __restrict__ xb, unsigned short* __restrict__ Wqb,
    unsigned short* __restrict__ Wkb, unsigned short* __restrict__ Wvb,
    unsigned short* __restrict__ Wob, float* __restrict__ scores) {
  if (blockIdx.x < NSCORE) {
    const int t = blockIdx.x * 4 + (threadIdx.x >> 6);
    const int lane = threadIdx.x & 63;
    const float* xrow = x + (size_t)t * C_DIM;
    float acc = 0.f;
    #pragma unroll 4
    for (int i = lane; i < C_DIM; i += 64)
      acc += xrow[i] * Wks[i];
    #pragma unroll
    for (int o = 32; o; o >>= 1) acc += __shfl_xor(acc, o);
    if (lane == 0) scores[t] = acc + bks[0];
    return;
  }
  const int i = (blockIdx.x - NSCORE) * 256 + threadIdx.x;
  const int NX4 = T_DIM * C_DIM / 4;
  const int NW4 = C_DIM * C_DIM / 4;
  const float* src;
  unsigned short* dst;
  int j = i;
  if (j < NX4) { src = x; dst = xb; }
  else {
    j -= NX4;
    int w = j / NW4;
    j -= w * NW4;
    src = (w == 0) ? Wq : (w == 1) ? Wk : (w == 2) ? Wv : Wo;
    dst = (w == 0) ? Wqb : (w == 1) ? Wkb : (w == 2) ? Wvb : Wob;
  }
  float4 f = reinterpret_cast<const float4*>(src)[j];
  ushort4 o;
  o.x = f2bfu(f.x); o.y = f2bfu(f.y); o.z = f2bfu(f.z); o.w = f2bfu(f.w);
  reinterpret_cast<ushort4*>(dst)[j] = o;
}

// ---- GEMM body: 128x64 tile, BK=128; LDS passed in (shared arena) ----
__device__ __forceinline__ void gemm_body_128x64(
    const unsigned short* __restrict__ A, const unsigned short* __restrict__ W,
    f32x4 acc[4][2], int bm, int bn, int tid,
    unsigned short* As, unsigned short* Ws) {
  const int w = tid >> 6, lane = tid & 63;
  const int quad = lane >> 4, r = lane & 15;
  const int wm = (w >> 1) * 64, wn = (w & 1) * 32;
  const int sub = lane >> 4;
  const int c = lane & 15;
  const unsigned short* Arow[8];
  const unsigned short* Wrow[4];
  #pragma unroll
  for (int i = 0; i < 8; ++i) {
    const int row = w * 32 + i * 4 + sub;
    Arow[i] = A + (size_t)(bm * GBM + row) * C_DIM + ((c ^ (row & 7)) * 8);
  }
  #pragma unroll
  for (int i = 0; i < 4; ++i) {
    const int row = w * 16 + i * 4 + sub;
    Wrow[i] = W + (size_t)(bn * GBN + row) * C_DIM + ((c ^ (row & 7)) * 8);
  }
  for (int kb = 0; kb < C_DIM; kb += GBK) {
    #pragma unroll
    for (int i = 0; i < 8; ++i)
      GLOAD_LDS16(Arow[i] + kb, &As[(w * 32 + i * 4) * GBK]);
    #pragma unroll
    for (int i = 0; i < 4; ++i)
      GLOAD_LDS16(Wrow[i] + kb, &Ws[(w * 16 + i * 4) * GBK]);
    __syncthreads();
    #pragma unroll
    for (int ks = 0; ks < 4; ++ks) {
      const int pc = ((ks * 4 + quad) ^ (r & 7)) * 8;
      short8 af[4], bfr[2];
      #pragma unroll
      for (int mi = 0; mi < 4; ++mi)
        af[mi] = *reinterpret_cast<const short8*>(&As[(wm + mi * 16 + r) * GBK + pc]);
      #pragma unroll
      for (int ni = 0; ni < 2; ++ni)
        bfr[ni] = *reinterpret_cast<const short8*>(&Ws[(wn + ni * 16 + r) * GBK + pc]);
      #pragma unroll
      for (int mi = 0; mi < 4; ++mi)
        #pragma unroll
        for (int ni = 0; ni < 2; ++ni)
          acc[mi][ni] = __builtin_amdgcn_mfma_f32_16x16x32_bf16(af[mi], bfr[ni], acc[mi][ni], 0, 0, 0);
    }
    __syncthreads();
  }
}

// ---- launch 2: rank_sort (blocks [0,512)) + fused QKV GEMM (rest).
// Rank and QKV have disjoint deps (both only need launch 1); rank blocks are
// tiny and run alongside the GEMM. LDS arena shared by both paths. ----
#define NRANK (T_DIM / 4)  // 512
__global__ __launch_bounds__(256) void gemm_qkv_rank_kernel(
    const unsigned short* __restrict__ A,
    const unsigned short* __restrict__ Wq, const unsigned short* __restrict__ Wk,
    const unsigned short* __restrict__ Wv,
    const float* __restrict__ bq, const float* __restrict__ bk,
    const float* __restrict__ bv,
    unsigned short* __restrict__ qo, unsigned short* __restrict__ ko,
    unsigned short* __restrict__ vo,
    const float* __restrict__ scores, int* __restrict__ sorted_idx) {
  __shared__ unsigned short lds[(GBM + GBN) * GBK];  // 48 KB arena
  const int tid = threadIdx.x;
  if (blockIdx.x < NRANK) {
    // rank-by-counting sort: one wave per element, lane-parallel scan
    float* ss = reinterpret_cast<float*>(lds);  // first 8 KB of arena
    for (int j = tid; j < T_DIM; j += 256) ss[j] = scores[j];
    __syncthreads();
    const int w = tid >> 6, lane = tid & 63;
    const int i = blockIdx.x * 4 + w;
    const float si = ss[i];
    int rank = 0;
    #pragma unroll
    for (int step = 0; step < T_DIM / 64; ++step) {
      const int j = step * 64 + lane;
      const float sj = ss[j];
      rank += (int)((sj > si) || (sj == si && j < i));
    }
    #pragma unroll
    for (int o = 32; o; o >>= 1) rank += __shfl_xor(rank, o);
    if (lane == 0) sorted_idx[rank] = i;
    return;
  }
  const int bid = blockIdx.x - NRANK;
  const int per = (T_DIM / GBM) * (C_DIM / GBN);  // 256
  const int which = bid / per;
  const int rem = bid % per;
  const int bm = rem / (C_DIM / GBN);
  const int bn = rem % (C_DIM / GBN);
  const unsigned short* W = (which == 0) ? Wq : (which == 1) ? Wk : Wv;
  const float* bias = (which == 0) ? bq : (which == 1) ? bk : bv;
  unsigned short* out = (which == 0) ? qo : (which == 1) ? ko : vo;
  f32x4 acc[4][2] = {};
  gemm_body_128x64(A, W, acc, bm, bn, tid, lds, lds + GBM * GBK);
  const int w = tid >> 6, lane = tid & 63;
  const int quad = lane >> 4, r = lane & 15;
  const int wm = (w >> 1) * 64, wn = (w & 1) * 32;
  #pragma unroll
  for (int mi = 0; mi < 4; ++mi) {
    #pragma unroll
    for (int ni = 0; ni < 2; ++ni) {
      const int col = bn * GBN + wn + ni * 16 + r;
      const float bf = bias[col];
      #pragma unroll
      for (int i = 0; i < 4; ++i) {
        const int row = bm * GBM + wm + mi * 16 + quad * 4 + i;
        const float val = acc[mi][ni][i] + bf;
        // q,k -> f16 (fdot2 path in attn); v -> bf16
        out[(size_t)row * C_DIM + col] = (which == 2) ? f2bfu(val) : f2h(val);
      }
    }
  }
}

// ---- o-proj GEMM body: 64x64 tile, BK=128 ----
__device__ __forceinline__ void gemm_body_64x64(
    const unsigned short* __restrict__ A, const unsigned short* __restrict__ W,
    f32x4 acc[2][2], int bm, int bn, int tid) {
  __shared__ unsigned short As[OBM * GBK];  // 16 KB
  __shared__ unsigned short Ws[OBN * GBK];  // 16 KB
  const int w = tid >> 6, lane = tid & 63;
  const int quad = lane >> 4, r = lane & 15;
  const int wm = (w >> 1) * 32, wn = (w & 1) * 32;
  const int sub = lane >> 4;
  const int c = lane & 15;
  const unsigned short* Arow[4];
  const unsigned short* Wrow[4];
  #pragma unroll
  for (int i = 0; i < 4; ++i) {
    const int row = w * 16 + i * 4 + sub;
    Arow[i] = A + (size_t)(bm * OBM + row) * C_DIM + ((c ^ (row & 7)) * 8);
    Wrow[i] = W + (size_t)(bn * OBN + row) * C_DIM + ((c ^ (row & 7)) * 8);
  }
  for (int kb = 0; kb < C_DIM; kb += GBK) {
    #pragma unroll
    for (int i = 0; i < 4; ++i)
      GLOAD_LDS16(Arow[i] + kb, &As[(w * 16 + i * 4) * GBK]);
    #pragma unroll
    for (int i = 0; i < 4; ++i)
      GLOAD_LDS16(Wrow[i] + kb, &Ws[(w * 16 + i * 4) * GBK]);
    __syncthreads();
    #pragma unroll
    for (int ks = 0; ks < 4; ++ks) {
      const int pc = ((ks * 4 + quad) ^ (r & 7)) * 8;
      short8 af[2], bfr[2];
      #pragma unroll
      for (int mi = 0; mi < 2; ++mi)
        af[mi] = *reinterpret_cast<const short8*>(&As[(wm + mi * 16 + r) * GBK + pc]);
      #pragma unroll
      for (int ni = 0; ni < 2; ++ni)
        bfr[ni] = *reinterpret_cast<const short8*>(&Ws[(wn + ni * 16 + r) * GBK + pc]);
      #pragma unroll
      for (int mi = 0; mi < 2; ++mi)
        #pragma unroll
        for (int ni = 0; ni < 2; ++ni)
          acc[mi][ni] = __builtin_amdgcn_mfma_f32_16x16x32_bf16(af[mi], bfr[ni], acc[mi][ni], 0, 0, 0);
    }
    __syncthreads();
  }
}

// ---- launch 5: output projection GEMM, fp32 out, 64x64 tile ----
__global__ __launch_bounds__(256) void gemm_o_f32_kernel(
    const unsigned short* __restrict__ A, const unsigned short* __restrict__ W,
    const float* __restrict__ bias, float* __restrict__ out) {
  const int tid = threadIdx.x;
  const int bm = blockIdx.x / (C_DIM / OBN);
  const int bn = blockIdx.x % (C_DIM / OBN);
  f32x4 acc[2][2] = {};
  gemm_body_64x64(A, W, acc, bm, bn, tid);
  const int w = tid >> 6, lane = tid & 63;
  const int quad = lane >> 4, r = lane & 15;
  const int wm = (w >> 1) * 32, wn = (w & 1) * 32;
  #pragma unroll
  for (int mi = 0; mi < 2; ++mi) {
    #pragma unroll
    for (int ni = 0; ni < 2; ++ni) {
      const int col = bn * OBN + wn + ni * 16 + r;
      const float bf = bias[col];
      #pragma unroll
      for (int i = 0; i < 4; ++i) {
        const int row = bm * OBM + wm + mi * 16 + quad * 4 + i;
        out[(size_t)row * C_DIM + col] = acc[mi][ni][i] + bf;
      }
    }
  }
}

// ---- launch 3: per-t top-64 selection table (one wave per t).
// Replaces the per-block redundant ballot-scan in the attention kernel:
// previously each of 8192 attn blocks staged 8 KB of sorted indices and every
// wave re-ran the 32-iter scan (16x redundancy per t). Now computed once per t
// (2048 waves total) into sel[t][64] holding pre-scaled row offsets. ----
__global__ __launch_bounds__(256) void select_kernel(
    const int* __restrict__ sorted_idx, int* __restrict__ sel) {
  const int tid = threadIdx.x;
  const int w = tid >> 6, lane = tid & 63;
  const int t = blockIdx.x * 4 + w;
  int* dst = sel + (size_t)t * KSP;
  if (t <= 63) {
    // positions 0..t-1 once, index t duplicated for the remainder — same
    // multiset as the reference's min(top_k_idx, t) clamp on -inf entries.
    dst[lane] = ((lane < t) ? lane : t) * C_DIM;
    return;
  }
  const unsigned long long lt_mask = (1ull << lane) - 1ull;
  int count = 0;
  for (int chunk = 0; chunk < T_DIM / 64 && count < KSP; ++chunk) {
    int s = sorted_idx[chunk * 64 + lane];
    s = (s < 0) ? 0 : (s > T_DIM - 1 ? T_DIM - 1 : s);
    const bool ok = (s <= t);
    const unsigned long long mm = __ballot(ok);
    const int pos = count + __popcll(mm & lt_mask);
    if (ok && pos < KSP) dst[pos] = s * C_DIM;
    count += __popcll(mm);
  }
}

// ---- launch 4: sparse attention, selection precomputed (no LDS, no syncs).
// Block per (t, head-group); wave per head. Q,K f16 fdot2 phase-1,
// V bf16 phase-2, all gathers up-front. ----
__global__ __launch_bounds__(256) void attn_kernel(
    const unsigned short* __restrict__ q, const unsigned short* __restrict__ k,
    const unsigned short* __restrict__ v, const int* __restrict__ sel,
    unsigned short* __restrict__ attn_out) {
  const int t = blockIdx.x >> 2;
  const int hg = blockIdx.x & 3;
  const int tid = threadIdx.x;
  const int w = tid >> 6, lane = tid & 63;
  const int h = hg * 4 + w;
  const int c8 = lane & 7;
  const int ksub = lane >> 3;
  const int hbase = h * HS + 8 * c8;
  const int* __restrict__ selt = sel + (size_t)t * KSP;
  uint4 qraw = *reinterpret_cast<const uint4*>(q + (size_t)t * C_DIM + hbase);
  int offr[8];
  #pragma unroll
  for (int jj = 0; jj < 8; ++jj) offr[jj] = selt[8 * jj + ksub];
  uint4 kraw[8], vraw[8];
  #pragma unroll
  for (int jj = 0; jj < 8; ++jj)
    kraw[jj] = *reinterpret_cast<const uint4*>(k + offr[jj] + hbase);
  #pragma unroll
  for (int jj = 0; jj < 8; ++jj)
    vraw[jj] = *reinterpret_cast<const uint4*>(v + offr[jj] + hbase);
  // phase 1: logits via f16 dot2, scale post-dot (exact pow2)
  float l[8];
  #pragma unroll
  for (int jj = 0; jj < 8; ++jj) {
    const uint4 raw = kraw[jj];
    float pl = dot2h(raw.x, qraw.x, 0.f);
    pl = dot2h(raw.y, qraw.y, pl);
    pl = dot2h(raw.z, qraw.z, pl);
    pl = dot2h(raw.w, qraw.w, pl);
    pl *= 0.125f;
    pl += __shfl_xor(pl, 1);
    pl += __shfl_xor(pl, 2);
    pl += __shfl_xor(pl, 4);
    l[jj] = pl;
  }
  float m = l[0];
  #pragma unroll
  for (int jj = 1; jj < 8; ++jj) m = fmaxf(m, l[jj]);
  m = fmaxf(m, __shfl_xor(m, 8));
  m = fmaxf(m, __shfl_xor(m, 16));
  m = fmaxf(m, __shfl_xor(m, 32));
  float sum = 0.f;
  #pragma unroll
  for (int jj = 0; jj < 8; ++jj) {
    l[jj] = __expf(l[jj] - m);
    sum += l[jj];
  }
  sum += __shfl_xor(sum, 8);
  sum += __shfl_xor(sum, 16);
  sum += __shfl_xor(sum, 32);
  const float rs = 1.0f / sum;
  // phase 2: weighted V (bf16) sum
  float a[8] = {0.f, 0.f, 0.f, 0.f, 0.f, 0.f, 0.f, 0.f};
  #pragma unroll
  for (int jj = 0; jj < 8; ++jj) {
    const uint4 raw = vraw[jj];
    const float p = l[jj] * rs;
    a[0] += p * bflo(raw.x); a[1] += p * bfhi(raw.x);
    a[2] += p * bflo(raw.y); a[3] += p * bfhi(raw.y);
    a[4] += p * bflo(raw.z); a[5] += p * bfhi(raw.z);
    a[6] += p * bflo(raw.w); a[7] += p * bfhi(raw.w);
  }
  #pragma unroll
  for (int o = 8; o <= 32; o <<= 1) {
    #pragma unroll
    for (int z = 0; z < 8; ++z) a[z] += __shfl_xor(a[z], o);
  }
  if (ksub == 0) {
    ushort4 o0, o1;
    o0.x = f2bfu(a[0]); o0.y = f2bfu(a[1]); o0.z = f2bfu(a[2]); o0.w = f2bfu(a[3]);
    o1.x = f2bfu(a[4]); o1.y = f2bfu(a[5]); o1.z = f2bfu(a[6]); o1.w = f2bfu(a[7]);
    ushort4* dst = reinterpret_cast<ushort4*>(attn_out + (size_t)t * C_DIM + hbase);
    dst[0] = o0;
    dst[1] = o1;
  }
}

extern "C" void kernel_launch(void* const* d_in, const int* in_sizes, int n_in,
                              void* d_out, int out_size, void* d_ws, size_t ws_size,
                              hipStream_t stream) {
  const float* x   = (const float*)d_in[0];
  const float* Wq  = (const float*)d_in[1];
  const float* bq  = (const float*)d_in[2];
  const float* Wk  = (const float*)d_in[3];
  const float* bk  = (const float*)d_in[4];
  const float* Wv  = (const float*)d_in[5];
  const float* bv  = (const float*)d_in[6];
  const float* Wo  = (const float*)d_in[7];
  const float* bo  = (const float*)d_in[8];
  const float* Wks = (const float*)d_in[9];
  const float* bks = (const float*)d_in[10];
  float* out = (float*)d_out;

  char* ws = (char*)d_ws;
  size_t off = 0;
  float* scores = (float*)(ws + off); off += 8192;
  int*   sorted = (int*)(ws + off);   off += 8192;
  int*   sel    = (int*)(ws + off);   off += (size_t)T_DIM * KSP * 4;  // 512 KB
  unsigned short* xb  = (unsigned short*)(ws + off); off += (size_t)T_DIM * C_DIM * 2;
  unsigned short* Wqb = (unsigned short*)(ws + off); off += (size_t)C_DIM * C_DIM * 2;
  unsigned short* Wkb = (unsigned short*)(ws + off); off += (size_t)C_DIM * C_DIM * 2;
  unsigned short* Wvb = (unsigned short*)(ws + off); off += (size_t)C_DIM * C_DIM * 2;
  unsigned short* Wob = (unsigned short*)(ws + off); off += (size_t)C_DIM * C_DIM * 2;
  unsigned short* qb  = (unsigned short*)(ws + off); off += (size_t)T_DIM * C_DIM * 2;
  unsigned short* kb  = (unsigned short*)(ws + off); off += (size_t)T_DIM * C_DIM * 2;
  unsigned short* vb  = (unsigned short*)(ws + off); off += (size_t)T_DIM * C_DIM * 2;
  unsigned short* ab  = xb;  // alias: xb dead after gemm_qkv

  // launch 1: conversion + scores
  convert_scores_kernel<<<NSCORE + NCONV, 256, 0, stream>>>(
      x, Wq, Wk, Wv, Wo, Wks, bks, xb, Wqb, Wkb, Wvb, Wob, scores);

  // launch 2: rank-sort (512 blocks) + fused QKV GEMM (768 blocks)
  gemm_qkv_rank_kernel<<<NRANK + 3 * (T_DIM / GBM) * (C_DIM / GBN), 256, 0,
                         stream>>>(
      xb, Wqb, Wkb, Wvb, bq, bk, bv, qb, kb, vb, scores, sorted);

  // launch 3: per-t top-64 selection table (one wave per t)
  select_kernel<<<T_DIM / 4, 256, 0, stream>>>(sorted, sel);

  // launch 4: attention, selection precomputed
  attn_kernel<<<T_DIM * 4, 256, 0, stream>>>(qb, kb, vb, sel, ab);

  // launch 5: output projection
  gemm_o_f32_kernel<<<(T_DIM / OBM) * (C_DIM / OBN), 256, 0, stream>>>(
      ab, Wob, bo, out);
}